// Round 8
// baseline (116.763 us; speedup 1.0000x reference)
//
#include <hip/hip_runtime.h>
#include <hip/hip_bf16.h>
#include <utility>

// Problem constants (fixed by the reference setup_inputs()).
#define J_     24
#define CIN_   32
#define COUT_  32
#define B_     8
#define T_     4096
#define R_     12
#define TT_    256                         // t per main-kernel block (4 waves x 64t)
#define POOLED_SZ_ (B_ * R_ * COUT_ * T_)  // 12,582,912
#define XT_ELEMS_  ((size_t)B_ * T_ * (J_ * CIN_))   // 25,165,824 bf16
#define NFRAG_     420                     // 70 edges * 3 kw * 2 co-tiles

typedef float  f32x4  __attribute__((ext_vector_type(4)));
typedef short  bf16x8 __attribute__((ext_vector_type(8)));
typedef unsigned short us8 __attribute__((ext_vector_type(8)));

// Compile-time adjacency (verified R1/R5): bit n of kAdjMask[i] <=> n in ADJ_LIST[i].
static constexpr unsigned kAdjMask[J_] = {
    0x0000000Fu, 0x00000013u, 0x00000025u, 0x00000049u, 0x00000092u, 0x00000124u,
    0x00000248u, 0x00000490u, 0x00000920u, 0x00007240u, 0x00000480u, 0x00000900u,
    0x00009200u, 0x00012200u, 0x00024200u, 0x00009000u, 0x00052000u, 0x000A4000u,
    0x00150000u, 0x002A0000u, 0x00540000u, 0x00A80000u, 0x00500000u, 0x00A00000u
};
static constexpr int kAdjOff[J_ + 1] = {
    0,4,7,10,13,16,19,22,25,28,33,35,37,40,43,46,48,51,54,57,60,63,66,68,70
};
// Flat edge index of (jout, nb), matching ADJ_FLAT's ascending-per-joint order.
static constexpr int edge_of(int jout, int nb) {
    return kAdjOff[jout] + __builtin_popcount(kAdjMask[jout] & ((1u << nb) - 1u));
}

// Device-side copies for the pack/aux kernel.
__device__ __constant__ unsigned int ADJMASK[J_] = {
    0x0000000Fu, 0x00000013u, 0x00000025u, 0x00000049u, 0x00000092u, 0x00000124u,
    0x00000248u, 0x00000490u, 0x00000920u, 0x00007240u, 0x00000480u, 0x00000900u,
    0x00009200u, 0x00012200u, 0x00024200u, 0x00009000u, 0x00052000u, 0x000A4000u,
    0x00150000u, 0x002A0000u, 0x00540000u, 0x00A80000u, 0x00500000u, 0x00A00000u
};
__device__ __constant__ int ADJ_FLAT[70] = {
    0,1,2,3,  0,1,4,  0,2,5,  0,3,6,  1,4,7,  2,5,8,  3,6,9,  4,7,10,  5,8,11,
    6,9,12,13,14,  7,10,  8,11,  9,12,15,  9,13,16,  9,14,17,  12,15,
    13,16,18,  14,17,19,  16,18,20,  17,19,21,  18,20,22,  19,21,23,  20,22,  21,23
};
__device__ __constant__ int ADJ_OFF[J_ + 1] = {
    0,4,7,10,13,16,19,22,25,28,33,35,37,40,43,46,48,51,54,57,60,63,66,68,70
};

static __device__ __forceinline__ unsigned short f2bf(float f) {
    unsigned u = __float_as_uint(f);
    unsigned r = (u + 0x7fffu + ((u >> 16) & 1u)) >> 16;   // RNE
    return (unsigned short)r;
}

// ---------------------------------------------------------------------------
// Pre-kernel 1: x fp32 [b][768][4096] -> xT bf16 [b][4096][768] via LDS tiles.
// (HBM-roofline already: 148 MB at ~6 TB/s.)
// ---------------------------------------------------------------------------
__global__ __launch_bounds__(256)
void skel_transpose(const float* __restrict__ x, unsigned short* __restrict__ xT)
{
    __shared__ float xs[32][257];
    const int tid = threadIdx.x;
    const int tt0 = blockIdx.x * 256;   // t tile
    const int cg  = blockIdx.y;         // channel group of 32 (0..23)
    const int b   = blockIdx.z;

    const float* xp = x + ((size_t)b * (J_ * CIN_) + cg * 32) * T_ + tt0;
#pragma unroll
    for (int i = 0; i < 8; ++i) {
        const int idx = tid + i * 256;
        const int row = idx >> 6;            // 0..31
        const int c4  = (idx & 63) << 2;     // 0..252
        const float4 v = *(const float4*)(xp + (size_t)row * T_ + c4);
        xs[row][c4 + 0] = v.x; xs[row][c4 + 1] = v.y;
        xs[row][c4 + 2] = v.z; xs[row][c4 + 3] = v.w;
    }
    __syncthreads();

    union { unsigned short u[32]; uint4 q[4]; } pk;
#pragma unroll
    for (int c = 0; c < 32; ++c) pk.u[c] = f2bf(xs[c][tid]);
    unsigned short* dst = xT + ((size_t)b * T_ + tt0 + tid) * (J_ * CIN_) + cg * 32;
#pragma unroll
    for (int k = 0; k < 4; ++k) *(uint4*)(dst + k * 8) = pk.q[k];
}

// ---------------------------------------------------------------------------
// Pre-kernel 2: pack masked W blocks into per-lane MFMA A-fragments (bf16),
// k-slot map identical to the B side: ci = (lane>>4)*8 + elem. Block 420
// additionally writes the REGIONS / POST_ADJ constant outputs.
// ---------------------------------------------------------------------------
__global__ __launch_bounds__(64)
void skel_pack(const float* __restrict__ W, unsigned short* __restrict__ wsW,
               float* __restrict__ out_regions, float* __restrict__ out_post)
{
    const int fb = blockIdx.x;
    const int l  = threadIdx.x;          // 0..63
    if (fb == NFRAG_) {
        for (int i = l; i < J_; i += 64) out_regions[i] = (float)i;
        for (int i = l; i < R_ * R_; i += 64) {
            const int r1 = i / R_, r2 = i - r1 * R_;
            const unsigned m = ADJMASK[2 * r1] | ADJMASK[2 * r1 + 1];
            out_post[i] = ((m >> (2 * r2)) & 3u) ? 1.0f : 0.0f;
        }
        return;
    }
    const int cot = fb & 1;
    const int tmp = fb >> 1;
    const int kw  = tmp % 3;
    const int e   = tmp / 3;             // 0..69 flat edge index
    int jout = 0;
    while (ADJ_OFF[jout + 1] <= e) ++jout;
    const int nb = ADJ_FLAT[e];
    const int co = cot * 16 + (l & 15);
    const int hi = l >> 4;

    union { unsigned short u[8]; uint4 q; } pk;
#pragma unroll
    for (int j = 0; j < 8; ++j) {
        const int ci = hi * 8 + j;
        const float w = W[((size_t)(jout * COUT_ + co) * (J_ * CIN_) + (nb * CIN_ + ci)) * 3 + kw];
        pk.u[j] = f2bf(w);
    }
    *(uint4*)(wsW + (size_t)fb * 512 + l * 8) = pk.q;
}

// ---------------------------------------------------------------------------
// Main kernel: fully compile-time-specialized per region. Each wave owns 64 t
// (4 x 16-t subtiles); per neighbor: 12 independent B-loads feed up to 48
// MFMAs with constexpr A-fragment offsets. No LDS, no barriers, no counters.
// ---------------------------------------------------------------------------
template<int RGN, int NB>
__device__ __forceinline__ void nb_step(const unsigned short* __restrict__ xTb,
                                        const unsigned short* __restrict__ wsWl,
                                        int tw, f32x4 acc[2][2][4])
{
    constexpr unsigned m0 = kAdjMask[2 * RGN], m1 = kAdjMask[2 * RGN + 1];
    constexpr bool e0 = (m0 >> NB) & 1u;
    constexpr bool e1 = (m1 >> NB) & 1u;
    if constexpr (!(e0 || e1)) return;

    // B fragments: 3 kw shifts x 4 subtiles, 16B/lane, all independent.
    bf16x8 bfr[3][4];
#pragma unroll
    for (int kw = 0; kw < 3; ++kw) {
#pragma unroll
        for (int sl = 0; sl < 4; ++sl) {
            const int t  = tw + sl * 16 + kw - 1;
            const int tc = t < 0 ? 0 : (t > T_ - 1 ? T_ - 1 : t);
            us8 v = *(const us8*)(xTb + (size_t)tc * (J_ * CIN_) + NB * CIN_);
            if ((unsigned)t >= (unsigned)T_) {
                const us8 z = {0, 0, 0, 0, 0, 0, 0, 0};
                v = z;
            }
            bfr[kw][sl] = (bf16x8)v;
        }
    }
    if constexpr (e0) {
        constexpr int E = edge_of(2 * RGN, NB);
#pragma unroll
        for (int kw = 0; kw < 3; ++kw)
#pragma unroll
            for (int cot = 0; cot < 2; ++cot) {
                const bf16x8 a = *(const bf16x8*)(wsWl + (size_t)(E * 6 + kw * 2 + cot) * 512);
#pragma unroll
                for (int sl = 0; sl < 4; ++sl)
                    acc[0][cot][sl] = __builtin_amdgcn_mfma_f32_16x16x32_bf16(
                        a, bfr[kw][sl], acc[0][cot][sl], 0, 0, 0);
            }
    }
    if constexpr (e1) {
        constexpr int E = edge_of(2 * RGN + 1, NB);
#pragma unroll
        for (int kw = 0; kw < 3; ++kw)
#pragma unroll
            for (int cot = 0; cot < 2; ++cot) {
                const bf16x8 a = *(const bf16x8*)(wsWl + (size_t)(E * 6 + kw * 2 + cot) * 512);
#pragma unroll
                for (int sl = 0; sl < 4; ++sl)
                    acc[1][cot][sl] = __builtin_amdgcn_mfma_f32_16x16x32_bf16(
                        a, bfr[kw][sl], acc[1][cot][sl], 0, 0, 0);
            }
    }
}

template<int RGN, int... NBs>
__device__ __forceinline__ void region_all(std::integer_sequence<int, NBs...>,
                                           const unsigned short* __restrict__ xTb,
                                           const unsigned short* __restrict__ wsWl,
                                           int tw, f32x4 acc[2][2][4])
{
    (nb_step<RGN, NBs>(xTb, wsWl, tw, acc), ...);
}

__global__ __launch_bounds__(256)
void skel_main(const unsigned short* __restrict__ xT,
               const unsigned short* __restrict__ wsW,
               const float* __restrict__ bias, float* __restrict__ out)
{
    // XCD-chunked swizzle (grid 1536 = 8*192, bijective): the 12 regions of a
    // (b,t-tile) group land on one XCD so shared xT rows stay L2-resident.
    const int i    = blockIdx.x;          // 0..1535
    const int xcd  = i & 7;
    const int slot = i >> 3;              // 0..191
    const int r    = slot % R_;
    const int gi   = slot / R_;           // 0..15
    const int g    = xcd + 8 * gi;        // (b,t-tile) group 0..127
    const int b    = g >> 4;
    const int t0   = (g & 15) * TT_;

    const int tid  = threadIdx.x;
    const int wv   = tid >> 6;
    const int lane = tid & 63;
    const int l15  = lane & 15;
    const int hi   = lane >> 4;

    f32x4 acc[2][2][4];                   // [joint][co_tile][subtile]
#pragma unroll
    for (int a = 0; a < 2; ++a)
#pragma unroll
        for (int c = 0; c < 2; ++c)
#pragma unroll
            for (int s = 0; s < 4; ++s) acc[a][c][s] = (f32x4){0.f, 0.f, 0.f, 0.f};

    const unsigned short* xTb  = xT + (size_t)b * T_ * (J_ * CIN_) + hi * 8;
    const unsigned short* wsWl = wsW + lane * 8;
    const int tw = t0 + wv * 64 + l15;    // lane's t for sl=0, kw=1

    using Seq = std::make_integer_sequence<int, J_>;
    switch (r) {
        case 0:  region_all<0>(Seq{}, xTb, wsWl, tw, acc); break;
        case 1:  region_all<1>(Seq{}, xTb, wsWl, tw, acc); break;
        case 2:  region_all<2>(Seq{}, xTb, wsWl, tw, acc); break;
        case 3:  region_all<3>(Seq{}, xTb, wsWl, tw, acc); break;
        case 4:  region_all<4>(Seq{}, xTb, wsWl, tw, acc); break;
        case 5:  region_all<5>(Seq{}, xTb, wsWl, tw, acc); break;
        case 6:  region_all<6>(Seq{}, xTb, wsWl, tw, acc); break;
        case 7:  region_all<7>(Seq{}, xTb, wsWl, tw, acc); break;
        case 8:  region_all<8>(Seq{}, xTb, wsWl, tw, acc); break;
        case 9:  region_all<9>(Seq{}, xTb, wsWl, tw, acc); break;
        case 10: region_all<10>(Seq{}, xTb, wsWl, tw, acc); break;
        default: region_all<11>(Seq{}, xTb, wsWl, tw, acc); break;
    }

    // Epilogue: bias + leakyReLU + pair mean. D layout: col=lane&15 (t),
    // row=(lane>>4)*4+q (co within 16-tile). [verified m89]
    const int j0 = 2 * r, j1 = 2 * r + 1;
#pragma unroll
    for (int cot = 0; cot < 2; ++cot) {
#pragma unroll
        for (int q = 0; q < 4; ++q) {
            const int co  = cot * 16 + hi * 4 + q;
            const float bb0 = bias[j0 * COUT_ + co];
            const float bb1 = bias[j1 * COUT_ + co];
            float* orow = out + ((size_t)b * (R_ * COUT_) + r * COUT_ + co) * T_
                          + t0 + wv * 64 + l15;
#pragma unroll
            for (int sl = 0; sl < 4; ++sl) {
                float y0 = acc[0][cot][sl][q] + bb0;
                y0 = (y0 > 0.f) ? y0 : 0.2f * y0;
                float y1 = acc[1][cot][sl][q] + bb1;
                y1 = (y1 > 0.f) ? y1 : 0.2f * y1;
                orow[sl * 16] = 0.5f * (y0 + y1);
            }
        }
    }
}

extern "C" void kernel_launch(void* const* d_in, const int* in_sizes, int n_in,
                              void* d_out, int out_size, void* d_ws, size_t ws_size,
                              hipStream_t stream)
{
    const float* x    = (const float*)d_in[0];
    const float* W    = (const float*)d_in[1];
    const float* bias = (const float*)d_in[2];
    float* out = (float*)d_out;

    unsigned short* xT  = (unsigned short*)d_ws;                 // 48 MiB bf16
    unsigned short* wsW = xT + XT_ELEMS_;                        // +420 KiB frags

    dim3 tgrid(T_ / 256, J_ * CIN_ / 32, B_);
    skel_transpose<<<tgrid, 256, 0, stream>>>(x, xT);

    float* out_regions = out + POOLED_SZ_;
    float* out_post    = out_regions + J_;
    skel_pack<<<NFRAG_ + 1, 64, 0, stream>>>(W, wsW, out_regions, out_post);

    skel_main<<<(T_ / TT_) * R_ * B_, 256, 0, stream>>>(xT, wsW, bias, out);
}

// Round 9
// 104.961 us; speedup vs baseline: 1.1124x; 1.1124x over previous
//
#include <hip/hip_runtime.h>
#include <hip/hip_bf16.h>
#include <utility>

// Problem constants (fixed by the reference setup_inputs()).
#define J_     24
#define CIN_   32
#define COUT_  32
#define B_     8
#define T_     4096
#define R_     12
#define TT_    256                         // t per main-kernel block (4 waves x 64t)
#define POOLED_SZ_ (B_ * R_ * COUT_ * T_)  // 12,582,912
#define XT_ELEMS_  ((size_t)B_ * T_ * (J_ * CIN_))   // 25,165,824 bf16
#define NFRAG_     420                     // 70 edges * 3 kw * 2 co-tiles

typedef float  f32x4  __attribute__((ext_vector_type(4)));
typedef short  bf16x8 __attribute__((ext_vector_type(8)));
typedef unsigned short us8 __attribute__((ext_vector_type(8)));

// Compile-time adjacency (verified R1/R5): bit n of kAdjMask[i] <=> n in ADJ_LIST[i].
static constexpr unsigned kAdjMask[J_] = {
    0x0000000Fu, 0x00000013u, 0x00000025u, 0x00000049u, 0x00000092u, 0x00000124u,
    0x00000248u, 0x00000490u, 0x00000920u, 0x00007240u, 0x00000480u, 0x00000900u,
    0x00009200u, 0x00012200u, 0x00024200u, 0x00009000u, 0x00052000u, 0x000A4000u,
    0x00150000u, 0x002A0000u, 0x00540000u, 0x00A80000u, 0x00500000u, 0x00A00000u
};
static constexpr int kAdjOff[J_ + 1] = {
    0,4,7,10,13,16,19,22,25,28,33,35,37,40,43,46,48,51,54,57,60,63,66,68,70
};
// Flat edge index of (jout, nb), matching the ascending-per-joint flat order.
static constexpr int edge_of(int jout, int nb) {
    return kAdjOff[jout] + __builtin_popcount(kAdjMask[jout] & ((1u << nb) - 1u));
}
static constexpr int nedges(int j) { return kAdjOff[j + 1] - kAdjOff[j]; }
// LDS slot base (in 1KB frags) for edge (2*RGN+js -> nb): j0's edges first, then j1's.
static constexpr int local_base(int RGN, int js, int nb) {
    const int j = 2 * RGN + js;
    const int within = edge_of(j, nb) - kAdjOff[j];
    const int pre = js ? nedges(2 * RGN) : 0;
    return (pre + within) * 6;
}

// Device-side copies for the pack/aux kernel + runtime staging.
__device__ __constant__ unsigned int ADJMASK[J_] = {
    0x0000000Fu, 0x00000013u, 0x00000025u, 0x00000049u, 0x00000092u, 0x00000124u,
    0x00000248u, 0x00000490u, 0x00000920u, 0x00007240u, 0x00000480u, 0x00000900u,
    0x00009200u, 0x00012200u, 0x00024200u, 0x00009000u, 0x00052000u, 0x000A4000u,
    0x00150000u, 0x002A0000u, 0x00540000u, 0x00A80000u, 0x00500000u, 0x00A00000u
};
__device__ __constant__ int ADJ_FLAT[70] = {
    0,1,2,3,  0,1,4,  0,2,5,  0,3,6,  1,4,7,  2,5,8,  3,6,9,  4,7,10,  5,8,11,
    6,9,12,13,14,  7,10,  8,11,  9,12,15,  9,13,16,  9,14,17,  12,15,
    13,16,18,  14,17,19,  16,18,20,  17,19,21,  18,20,22,  19,21,23,  20,22,  21,23
};
__device__ __constant__ int ADJ_OFF[J_ + 1] = {
    0,4,7,10,13,16,19,22,25,28,33,35,37,40,43,46,48,51,54,57,60,63,66,68,70
};

static __device__ __forceinline__ unsigned short f2bf(float f) {
    unsigned u = __float_as_uint(f);
    unsigned r = (u + 0x7fffu + ((u >> 16) & 1u)) >> 16;   // RNE
    return (unsigned short)r;
}

// ---------------------------------------------------------------------------
// Pre-kernel 1: x fp32 [b][768][4096] -> xT bf16 [b][4096][768] via LDS tiles.
// (Already ~HBM-roofline: 148 MB at ~6 TB/s.)
// ---------------------------------------------------------------------------
__global__ __launch_bounds__(256)
void skel_transpose(const float* __restrict__ x, unsigned short* __restrict__ xT)
{
    __shared__ float xs[32][257];
    const int tid = threadIdx.x;
    const int tt0 = blockIdx.x * 256;   // t tile
    const int cg  = blockIdx.y;         // channel group of 32 (0..23)
    const int b   = blockIdx.z;

    const float* xp = x + ((size_t)b * (J_ * CIN_) + cg * 32) * T_ + tt0;
#pragma unroll
    for (int i = 0; i < 8; ++i) {
        const int idx = tid + i * 256;
        const int row = idx >> 6;            // 0..31
        const int c4  = (idx & 63) << 2;     // 0..252
        const float4 v = *(const float4*)(xp + (size_t)row * T_ + c4);
        xs[row][c4 + 0] = v.x; xs[row][c4 + 1] = v.y;
        xs[row][c4 + 2] = v.z; xs[row][c4 + 3] = v.w;
    }
    __syncthreads();

    union { unsigned short u[32]; uint4 q[4]; } pk;
#pragma unroll
    for (int c = 0; c < 32; ++c) pk.u[c] = f2bf(xs[c][tid]);
    unsigned short* dst = xT + ((size_t)b * T_ + tt0 + tid) * (J_ * CIN_) + cg * 32;
#pragma unroll
    for (int k = 0; k < 4; ++k) *(uint4*)(dst + k * 8) = pk.q[k];
}

// ---------------------------------------------------------------------------
// Pre-kernel 2: pack masked W blocks into per-lane MFMA A-fragments (bf16),
// k-slot map identical to the B side: ci = (lane>>4)*8 + elem. Block 420
// additionally writes the REGIONS / POST_ADJ constant outputs.
// ---------------------------------------------------------------------------
__global__ __launch_bounds__(64)
void skel_pack(const float* __restrict__ W, unsigned short* __restrict__ wsW,
               float* __restrict__ out_regions, float* __restrict__ out_post)
{
    const int fb = blockIdx.x;
    const int l  = threadIdx.x;          // 0..63
    if (fb == NFRAG_) {
        for (int i = l; i < J_; i += 64) out_regions[i] = (float)i;
        for (int i = l; i < R_ * R_; i += 64) {
            const int r1 = i / R_, r2 = i - r1 * R_;
            const unsigned m = ADJMASK[2 * r1] | ADJMASK[2 * r1 + 1];
            out_post[i] = ((m >> (2 * r2)) & 3u) ? 1.0f : 0.0f;
        }
        return;
    }
    const int cot = fb & 1;
    const int tmp = fb >> 1;
    const int kw  = tmp % 3;
    const int e   = tmp / 3;             // 0..69 flat edge index
    int jout = 0;
    while (ADJ_OFF[jout + 1] <= e) ++jout;
    const int nb = ADJ_FLAT[e];
    const int co = cot * 16 + (l & 15);
    const int hi = l >> 4;

    union { unsigned short u[8]; uint4 q; } pk;
#pragma unroll
    for (int j = 0; j < 8; ++j) {
        const int ci = hi * 8 + j;
        const float w = W[((size_t)(jout * COUT_ + co) * (J_ * CIN_) + (nb * CIN_ + ci)) * 3 + kw];
        pk.u[j] = f2bf(w);
    }
    *(uint4*)(wsW + (size_t)fb * 512 + l * 8) = pk.q;
}

// ---------------------------------------------------------------------------
// Main kernel. A-fragments staged once into LDS (<=48KB/region), consumed via
// ds_read_b128 at compile-time immediate offsets. B from global with 12-wide
// MLP per neighbor step. Compile-time specialized per region.
// ---------------------------------------------------------------------------
template<int RGN, int NB>
__device__ __forceinline__ void nb_step(const unsigned short* __restrict__ xTb,
                                        const unsigned short* __restrict__ ldsl,
                                        int tw, f32x4 acc[2][2][4])
{
    constexpr unsigned m0 = kAdjMask[2 * RGN], m1 = kAdjMask[2 * RGN + 1];
    constexpr bool e0 = (m0 >> NB) & 1u;
    constexpr bool e1 = (m1 >> NB) & 1u;
    if constexpr (!(e0 || e1)) return;

    // B fragments: 3 kw shifts x 4 subtiles, 16B/lane, all independent.
    bf16x8 bfr[3][4];
#pragma unroll
    for (int kw = 0; kw < 3; ++kw) {
#pragma unroll
        for (int sl = 0; sl < 4; ++sl) {
            const int t  = tw + sl * 16 + kw - 1;
            const int tc = t < 0 ? 0 : (t > T_ - 1 ? T_ - 1 : t);
            us8 v = *(const us8*)(xTb + (size_t)tc * (J_ * CIN_) + NB * CIN_);
            if ((unsigned)t >= (unsigned)T_) {
                const us8 z = {0, 0, 0, 0, 0, 0, 0, 0};
                v = z;
            }
            bfr[kw][sl] = (bf16x8)v;
        }
    }
    if constexpr (e0) {
        constexpr int LB = local_base(RGN, 0, NB);
#pragma unroll
        for (int kw = 0; kw < 3; ++kw)
#pragma unroll
            for (int cot = 0; cot < 2; ++cot) {
                const bf16x8 a = *(const bf16x8*)(ldsl + (size_t)(LB + kw * 2 + cot) * 512);
#pragma unroll
                for (int sl = 0; sl < 4; ++sl)
                    acc[0][cot][sl] = __builtin_amdgcn_mfma_f32_16x16x32_bf16(
                        a, bfr[kw][sl], acc[0][cot][sl], 0, 0, 0);
            }
    }
    if constexpr (e1) {
        constexpr int LB = local_base(RGN, 1, NB);
#pragma unroll
        for (int kw = 0; kw < 3; ++kw)
#pragma unroll
            for (int cot = 0; cot < 2; ++cot) {
                const bf16x8 a = *(const bf16x8*)(ldsl + (size_t)(LB + kw * 2 + cot) * 512);
#pragma unroll
                for (int sl = 0; sl < 4; ++sl)
                    acc[1][cot][sl] = __builtin_amdgcn_mfma_f32_16x16x32_bf16(
                        a, bfr[kw][sl], acc[1][cot][sl], 0, 0, 0);
            }
    }
}

template<int RGN, int... NBs>
__device__ __forceinline__ void region_all(std::integer_sequence<int, NBs...>,
                                           const unsigned short* __restrict__ xTb,
                                           const unsigned short* __restrict__ ldsl,
                                           int tw, f32x4 acc[2][2][4])
{
    (nb_step<RGN, NBs>(xTb, ldsl, tw, acc), ...);
}

__global__ __launch_bounds__(256)
void skel_main(const unsigned short* __restrict__ xT,
               const unsigned short* __restrict__ wsW,
               const float* __restrict__ bias, float* __restrict__ out)
{
    // XCD-chunked swizzle (grid 1536 = 8*192, bijective): the 12 regions of a
    // (b,t-tile) group land on one XCD so shared xT rows stay L2-resident.
    const int i    = blockIdx.x;          // 0..1535
    const int xcd  = i & 7;
    const int slot = i >> 3;              // 0..191
    const int r    = slot % R_;
    const int gi   = slot / R_;           // 0..15
    const int g    = xcd + 8 * gi;        // (b,t-tile) group 0..127
    const int b    = g >> 4;
    const int t0   = (g & 15) * TT_;

    const int tid  = threadIdx.x;
    const int wv   = tid >> 6;
    const int lane = tid & 63;
    const int l15  = lane & 15;
    const int hi   = lane >> 4;

    // --- Stage this region's A-fragments into LDS (coalesced uint4 copy). ---
    __shared__ uint4 ldsAq[3072];          // 48 KB: max 8 edges * 6 frags * 1KB
    const int j0 = 2 * r, j1 = 2 * r + 1;
    const int n0 = ADJ_OFF[j0 + 1] - ADJ_OFF[j0];
    const int n1 = ADJ_OFF[j1 + 1] - ADJ_OFF[j1];
    {
        const uint4* s0 = (const uint4*)(wsW + (size_t)ADJ_OFF[j0] * 6 * 512);
        const uint4* s1 = (const uint4*)(wsW + (size_t)ADJ_OFF[j1] * 6 * 512);
        const int q0 = n0 * 384;           // 1KB frag = 64 uint4
        const int q1 = n1 * 384;
        for (int c = tid; c < q0; c += 256) ldsAq[c] = s0[c];
        for (int c = tid; c < q1; c += 256) ldsAq[q0 + c] = s1[c];
    }
    __syncthreads();

    f32x4 acc[2][2][4];                   // [joint][co_tile][subtile]
#pragma unroll
    for (int a = 0; a < 2; ++a)
#pragma unroll
        for (int c = 0; c < 2; ++c)
#pragma unroll
            for (int s = 0; s < 4; ++s) acc[a][c][s] = (f32x4){0.f, 0.f, 0.f, 0.f};

    const unsigned short* xTb  = xT + (size_t)b * T_ * (J_ * CIN_) + hi * 8;
    const unsigned short* ldsl = (const unsigned short*)ldsAq + lane * 8;
    const int tw = t0 + wv * 64 + l15;    // lane's t for sl=0, kw=1

    using Seq = std::make_integer_sequence<int, J_>;
    switch (r) {
        case 0:  region_all<0>(Seq{}, xTb, ldsl, tw, acc); break;
        case 1:  region_all<1>(Seq{}, xTb, ldsl, tw, acc); break;
        case 2:  region_all<2>(Seq{}, xTb, ldsl, tw, acc); break;
        case 3:  region_all<3>(Seq{}, xTb, ldsl, tw, acc); break;
        case 4:  region_all<4>(Seq{}, xTb, ldsl, tw, acc); break;
        case 5:  region_all<5>(Seq{}, xTb, ldsl, tw, acc); break;
        case 6:  region_all<6>(Seq{}, xTb, ldsl, tw, acc); break;
        case 7:  region_all<7>(Seq{}, xTb, ldsl, tw, acc); break;
        case 8:  region_all<8>(Seq{}, xTb, ldsl, tw, acc); break;
        case 9:  region_all<9>(Seq{}, xTb, ldsl, tw, acc); break;
        case 10: region_all<10>(Seq{}, xTb, ldsl, tw, acc); break;
        default: region_all<11>(Seq{}, xTb, ldsl, tw, acc); break;
    }

    // Epilogue: bias + leakyReLU + pair mean. D layout: col=lane&15 (t),
    // row=(lane>>4)*4+q (co within 16-tile). [verified m89]
#pragma unroll
    for (int cot = 0; cot < 2; ++cot) {
#pragma unroll
        for (int q = 0; q < 4; ++q) {
            const int co  = cot * 16 + hi * 4 + q;
            const float bb0 = bias[j0 * COUT_ + co];
            const float bb1 = bias[j1 * COUT_ + co];
            float* orow = out + ((size_t)b * (R_ * COUT_) + r * COUT_ + co) * T_
                          + t0 + wv * 64 + l15;
#pragma unroll
            for (int sl = 0; sl < 4; ++sl) {
                float y0 = acc[0][cot][sl][q] + bb0;
                y0 = (y0 > 0.f) ? y0 : 0.2f * y0;
                float y1 = acc[1][cot][sl][q] + bb1;
                y1 = (y1 > 0.f) ? y1 : 0.2f * y1;
                orow[sl * 16] = 0.5f * (y0 + y1);
            }
        }
    }
}

extern "C" void kernel_launch(void* const* d_in, const int* in_sizes, int n_in,
                              void* d_out, int out_size, void* d_ws, size_t ws_size,
                              hipStream_t stream)
{
    const float* x    = (const float*)d_in[0];
    const float* W    = (const float*)d_in[1];
    const float* bias = (const float*)d_in[2];
    float* out = (float*)d_out;

    unsigned short* xT  = (unsigned short*)d_ws;                 // 48 MiB bf16
    unsigned short* wsW = xT + XT_ELEMS_;                        // +420 KiB frags

    dim3 tgrid(T_ / 256, J_ * CIN_ / 32, B_);
    skel_transpose<<<tgrid, 256, 0, stream>>>(x, xT);

    float* out_regions = out + POOLED_SZ_;
    float* out_post    = out_regions + J_;
    skel_pack<<<NFRAG_ + 1, 64, 0, stream>>>(W, wsW, out_regions, out_post);

    skel_main<<<(T_ / TT_) * R_ * B_, 256, 0, stream>>>(xT, wsW, bias, out);
}

// Round 10
// 102.238 us; speedup vs baseline: 1.1421x; 1.0266x over previous
//
#include <hip/hip_runtime.h>
#include <hip/hip_bf16.h>
#include <utility>

// Problem constants (fixed by the reference setup_inputs()).
#define J_     24
#define CIN_   32
#define COUT_  32
#define B_     8
#define T_     4096
#define R_     12
#define TT_    256                         // t per main-kernel block (8 waves x 32t)
#define POOLED_SZ_ (B_ * R_ * COUT_ * T_)  // 12,582,912
#define XT_ELEMS_  ((size_t)B_ * T_ * (J_ * CIN_))   // 25,165,824 bf16
#define NFRAG_     420                     // 70 edges * 3 kw * 2 co-tiles

typedef float  f32x4  __attribute__((ext_vector_type(4)));
typedef short  bf16x8 __attribute__((ext_vector_type(8)));
typedef unsigned short us8 __attribute__((ext_vector_type(8)));

// Compile-time adjacency (verified R1/R5): bit n of kAdjMask[i] <=> n in ADJ_LIST[i].
static constexpr unsigned kAdjMask[J_] = {
    0x0000000Fu, 0x00000013u, 0x00000025u, 0x00000049u, 0x00000092u, 0x00000124u,
    0x00000248u, 0x00000490u, 0x00000920u, 0x00007240u, 0x00000480u, 0x00000900u,
    0x00009200u, 0x00012200u, 0x00024200u, 0x00009000u, 0x00052000u, 0x000A4000u,
    0x00150000u, 0x002A0000u, 0x00540000u, 0x00A80000u, 0x00500000u, 0x00A00000u
};
static constexpr int kAdjOff[J_ + 1] = {
    0,4,7,10,13,16,19,22,25,28,33,35,37,40,43,46,48,51,54,57,60,63,66,68,70
};
// Flat edge index of (jout, nb), matching the ascending-per-joint flat order.
static constexpr int edge_of(int jout, int nb) {
    return kAdjOff[jout] + __builtin_popcount(kAdjMask[jout] & ((1u << nb) - 1u));
}
static constexpr int nedges(int j) { return kAdjOff[j + 1] - kAdjOff[j]; }
// LDS slot base (in 1KB frags) for edge (2*RGN+js -> nb): j0's edges first, then j1's.
static constexpr int local_base(int RGN, int js, int nb) {
    const int j = 2 * RGN + js;
    const int within = edge_of(j, nb) - kAdjOff[j];
    const int pre = js ? nedges(2 * RGN) : 0;
    return (pre + within) * 6;
}

// Device-side copies for the pack/aux kernel + runtime staging.
__device__ __constant__ unsigned int ADJMASK[J_] = {
    0x0000000Fu, 0x00000013u, 0x00000025u, 0x00000049u, 0x00000092u, 0x00000124u,
    0x00000248u, 0x00000490u, 0x00000920u, 0x00007240u, 0x00000480u, 0x00000900u,
    0x00009200u, 0x00012200u, 0x00024200u, 0x00009000u, 0x00052000u, 0x000A4000u,
    0x00150000u, 0x002A0000u, 0x00540000u, 0x00A80000u, 0x00500000u, 0x00A00000u
};
__device__ __constant__ int ADJ_FLAT[70] = {
    0,1,2,3,  0,1,4,  0,2,5,  0,3,6,  1,4,7,  2,5,8,  3,6,9,  4,7,10,  5,8,11,
    6,9,12,13,14,  7,10,  8,11,  9,12,15,  9,13,16,  9,14,17,  12,15,
    13,16,18,  14,17,19,  16,18,20,  17,19,21,  18,20,22,  19,21,23,  20,22,  21,23
};
__device__ __constant__ int ADJ_OFF[J_ + 1] = {
    0,4,7,10,13,16,19,22,25,28,33,35,37,40,43,46,48,51,54,57,60,63,66,68,70
};

static __device__ __forceinline__ unsigned short f2bf(float f) {
    unsigned u = __float_as_uint(f);
    unsigned r = (u + 0x7fffu + ((u >> 16) & 1u)) >> 16;   // RNE
    return (unsigned short)r;
}

// ---------------------------------------------------------------------------
// Pre-kernel 1: x fp32 [b][768][4096] -> xT bf16 [b][4096][768] via LDS tiles.
// (Already ~HBM-roofline: 148 MB at ~6 TB/s.)
// ---------------------------------------------------------------------------
__global__ __launch_bounds__(256)
void skel_transpose(const float* __restrict__ x, unsigned short* __restrict__ xT)
{
    __shared__ float xs[32][257];
    const int tid = threadIdx.x;
    const int tt0 = blockIdx.x * 256;   // t tile
    const int cg  = blockIdx.y;         // channel group of 32 (0..23)
    const int b   = blockIdx.z;

    const float* xp = x + ((size_t)b * (J_ * CIN_) + cg * 32) * T_ + tt0;
#pragma unroll
    for (int i = 0; i < 8; ++i) {
        const int idx = tid + i * 256;
        const int row = idx >> 6;            // 0..31
        const int c4  = (idx & 63) << 2;     // 0..252
        const float4 v = *(const float4*)(xp + (size_t)row * T_ + c4);
        xs[row][c4 + 0] = v.x; xs[row][c4 + 1] = v.y;
        xs[row][c4 + 2] = v.z; xs[row][c4 + 3] = v.w;
    }
    __syncthreads();

    union { unsigned short u[32]; uint4 q[4]; } pk;
#pragma unroll
    for (int c = 0; c < 32; ++c) pk.u[c] = f2bf(xs[c][tid]);
    unsigned short* dst = xT + ((size_t)b * T_ + tt0 + tid) * (J_ * CIN_) + cg * 32;
#pragma unroll
    for (int k = 0; k < 4; ++k) *(uint4*)(dst + k * 8) = pk.q[k];
}

// ---------------------------------------------------------------------------
// Pre-kernel 2: pack masked W blocks into per-lane MFMA A-fragments (bf16),
// k-slot map identical to the B side: ci = (lane>>4)*8 + elem. Block 420
// additionally writes the REGIONS / POST_ADJ constant outputs.
// ---------------------------------------------------------------------------
__global__ __launch_bounds__(64)
void skel_pack(const float* __restrict__ W, unsigned short* __restrict__ wsW,
               float* __restrict__ out_regions, float* __restrict__ out_post)
{
    const int fb = blockIdx.x;
    const int l  = threadIdx.x;          // 0..63
    if (fb == NFRAG_) {
        for (int i = l; i < J_; i += 64) out_regions[i] = (float)i;
        for (int i = l; i < R_ * R_; i += 64) {
            const int r1 = i / R_, r2 = i - r1 * R_;
            const unsigned m = ADJMASK[2 * r1] | ADJMASK[2 * r1 + 1];
            out_post[i] = ((m >> (2 * r2)) & 3u) ? 1.0f : 0.0f;
        }
        return;
    }
    const int cot = fb & 1;
    const int tmp = fb >> 1;
    const int kw  = tmp % 3;
    const int e   = tmp / 3;             // 0..69 flat edge index
    int jout = 0;
    while (ADJ_OFF[jout + 1] <= e) ++jout;
    const int nb = ADJ_FLAT[e];
    const int co = cot * 16 + (l & 15);
    const int hi = l >> 4;

    union { unsigned short u[8]; uint4 q; } pk;
#pragma unroll
    for (int j = 0; j < 8; ++j) {
        const int ci = hi * 8 + j;
        const float w = W[((size_t)(jout * COUT_ + co) * (J_ * CIN_) + (nb * CIN_ + ci)) * 3 + kw];
        pk.u[j] = f2bf(w);
    }
    *(uint4*)(wsW + (size_t)fb * 512 + l * 8) = pk.q;
}

// ---------------------------------------------------------------------------
// Main kernel. 8 waves x 32t each (2 subtiles): small per-wave state so the
// full 6-load B-batch + next-step prefetch fit in registers, 2x wave count
// for latency hiding. A-fragments in LDS via compile-time immediate offsets.
// ---------------------------------------------------------------------------
template<int RGN, int NB>
__device__ __forceinline__ void nb_step(const unsigned short* __restrict__ xTb,
                                        const unsigned short* __restrict__ ldsl,
                                        int tw, f32x4 acc[2][2][2])
{
    constexpr unsigned m0 = kAdjMask[2 * RGN], m1 = kAdjMask[2 * RGN + 1];
    constexpr bool e0 = (m0 >> NB) & 1u;
    constexpr bool e1 = (m1 >> NB) & 1u;
    if constexpr (!(e0 || e1)) return;

    // B fragments: 3 kw shifts x 2 subtiles, 16B/lane, all independent.
    bf16x8 bfr[3][2];
#pragma unroll
    for (int kw = 0; kw < 3; ++kw) {
#pragma unroll
        for (int sl = 0; sl < 2; ++sl) {
            const int t  = tw + sl * 16 + kw - 1;
            const int tc = t < 0 ? 0 : (t > T_ - 1 ? T_ - 1 : t);
            us8 v = *(const us8*)(xTb + (size_t)tc * (J_ * CIN_) + NB * CIN_);
            if ((unsigned)t >= (unsigned)T_) {
                const us8 z = {0, 0, 0, 0, 0, 0, 0, 0};
                v = z;
            }
            bfr[kw][sl] = (bf16x8)v;
        }
    }
    if constexpr (e0) {
        constexpr int LB = local_base(RGN, 0, NB);
#pragma unroll
        for (int kw = 0; kw < 3; ++kw)
#pragma unroll
            for (int cot = 0; cot < 2; ++cot) {
                const bf16x8 a = *(const bf16x8*)(ldsl + (size_t)(LB + kw * 2 + cot) * 512);
#pragma unroll
                for (int sl = 0; sl < 2; ++sl)
                    acc[0][cot][sl] = __builtin_amdgcn_mfma_f32_16x16x32_bf16(
                        a, bfr[kw][sl], acc[0][cot][sl], 0, 0, 0);
            }
    }
    if constexpr (e1) {
        constexpr int LB = local_base(RGN, 1, NB);
#pragma unroll
        for (int kw = 0; kw < 3; ++kw)
#pragma unroll
            for (int cot = 0; cot < 2; ++cot) {
                const bf16x8 a = *(const bf16x8*)(ldsl + (size_t)(LB + kw * 2 + cot) * 512);
#pragma unroll
                for (int sl = 0; sl < 2; ++sl)
                    acc[1][cot][sl] = __builtin_amdgcn_mfma_f32_16x16x32_bf16(
                        a, bfr[kw][sl], acc[1][cot][sl], 0, 0, 0);
            }
    }
}

template<int RGN, int... NBs>
__device__ __forceinline__ void region_all(std::integer_sequence<int, NBs...>,
                                           const unsigned short* __restrict__ xTb,
                                           const unsigned short* __restrict__ ldsl,
                                           int tw, f32x4 acc[2][2][2])
{
    (nb_step<RGN, NBs>(xTb, ldsl, tw, acc), ...);
}

__global__ __launch_bounds__(512, 4)
void skel_main(const unsigned short* __restrict__ xT,
               const unsigned short* __restrict__ wsW,
               const float* __restrict__ bias, float* __restrict__ out)
{
    // XCD-chunked swizzle (grid 1536 = 8*192, bijective): the 12 regions of a
    // (b,t-tile) group land on one XCD so shared xT rows stay L2-resident.
    const int i    = blockIdx.x;          // 0..1535
    const int xcd  = i & 7;
    const int slot = i >> 3;              // 0..191
    const int r    = slot % R_;
    const int gi   = slot / R_;           // 0..15
    const int g    = xcd + 8 * gi;        // (b,t-tile) group 0..127
    const int b    = g >> 4;
    const int t0   = (g & 15) * TT_;

    const int tid  = threadIdx.x;
    const int wv   = tid >> 6;            // 0..7
    const int lane = tid & 63;
    const int l15  = lane & 15;
    const int hi   = lane >> 4;

    // --- Stage this region's A-fragments into LDS (coalesced uint4 copy). ---
    __shared__ uint4 ldsAq[3072];          // 48 KB: max 8 edges * 6 frags * 1KB
    const int j0 = 2 * r, j1 = 2 * r + 1;
    const int n0 = ADJ_OFF[j0 + 1] - ADJ_OFF[j0];
    const int n1 = ADJ_OFF[j1 + 1] - ADJ_OFF[j1];
    {
        const uint4* s0 = (const uint4*)(wsW + (size_t)ADJ_OFF[j0] * 6 * 512);
        const uint4* s1 = (const uint4*)(wsW + (size_t)ADJ_OFF[j1] * 6 * 512);
        const int q0 = n0 * 384;           // 1KB frag = 64 uint4
        const int q1 = n1 * 384;
        for (int c = tid; c < q0; c += 512) ldsAq[c] = s0[c];
        for (int c = tid; c < q1; c += 512) ldsAq[q0 + c] = s1[c];
    }
    __syncthreads();

    f32x4 acc[2][2][2];                   // [joint][co_tile][subtile]
#pragma unroll
    for (int a = 0; a < 2; ++a)
#pragma unroll
        for (int c = 0; c < 2; ++c)
#pragma unroll
            for (int s = 0; s < 2; ++s) acc[a][c][s] = (f32x4){0.f, 0.f, 0.f, 0.f};

    const unsigned short* xTb  = xT + (size_t)b * T_ * (J_ * CIN_) + hi * 8;
    const unsigned short* ldsl = (const unsigned short*)ldsAq + lane * 8;
    const int tw = t0 + wv * 32 + l15;    // lane's t for sl=0, kw=1

    using Seq = std::make_integer_sequence<int, J_>;
    switch (r) {
        case 0:  region_all<0>(Seq{}, xTb, ldsl, tw, acc); break;
        case 1:  region_all<1>(Seq{}, xTb, ldsl, tw, acc); break;
        case 2:  region_all<2>(Seq{}, xTb, ldsl, tw, acc); break;
        case 3:  region_all<3>(Seq{}, xTb, ldsl, tw, acc); break;
        case 4:  region_all<4>(Seq{}, xTb, ldsl, tw, acc); break;
        case 5:  region_all<5>(Seq{}, xTb, ldsl, tw, acc); break;
        case 6:  region_all<6>(Seq{}, xTb, ldsl, tw, acc); break;
        case 7:  region_all<7>(Seq{}, xTb, ldsl, tw, acc); break;
        case 8:  region_all<8>(Seq{}, xTb, ldsl, tw, acc); break;
        case 9:  region_all<9>(Seq{}, xTb, ldsl, tw, acc); break;
        case 10: region_all<10>(Seq{}, xTb, ldsl, tw, acc); break;
        default: region_all<11>(Seq{}, xTb, ldsl, tw, acc); break;
    }

    // Epilogue: bias + leakyReLU + pair mean. D layout: col=lane&15 (t),
    // row=(lane>>4)*4+q (co within 16-tile). [verified m89]
#pragma unroll
    for (int cot = 0; cot < 2; ++cot) {
#pragma unroll
        for (int q = 0; q < 4; ++q) {
            const int co  = cot * 16 + hi * 4 + q;
            const float bb0 = bias[j0 * COUT_ + co];
            const float bb1 = bias[j1 * COUT_ + co];
            float* orow = out + ((size_t)b * (R_ * COUT_) + r * COUT_ + co) * T_
                          + t0 + wv * 32 + l15;
#pragma unroll
            for (int sl = 0; sl < 2; ++sl) {
                float y0 = acc[0][cot][sl][q] + bb0;
                y0 = (y0 > 0.f) ? y0 : 0.2f * y0;
                float y1 = acc[1][cot][sl][q] + bb1;
                y1 = (y1 > 0.f) ? y1 : 0.2f * y1;
                orow[sl * 16] = 0.5f * (y0 + y1);
            }
        }
    }
}

extern "C" void kernel_launch(void* const* d_in, const int* in_sizes, int n_in,
                              void* d_out, int out_size, void* d_ws, size_t ws_size,
                              hipStream_t stream)
{
    const float* x    = (const float*)d_in[0];
    const float* W    = (const float*)d_in[1];
    const float* bias = (const float*)d_in[2];
    float* out = (float*)d_out;

    unsigned short* xT  = (unsigned short*)d_ws;                 // 48 MiB bf16
    unsigned short* wsW = xT + XT_ELEMS_;                        // +420 KiB frags

    dim3 tgrid(T_ / 256, J_ * CIN_ / 32, B_);
    skel_transpose<<<tgrid, 256, 0, stream>>>(x, xT);

    float* out_regions = out + POOLED_SZ_;
    float* out_post    = out_regions + J_;
    skel_pack<<<NFRAG_ + 1, 64, 0, stream>>>(W, wsW, out_regions, out_post);

    skel_main<<<(T_ / TT_) * R_ * B_, 512, 0, stream>>>(xT, wsW, bias, out);
}

// Round 11
// 102.070 us; speedup vs baseline: 1.1439x; 1.0016x over previous
//
#include <hip/hip_runtime.h>
#include <hip/hip_bf16.h>
#include <utility>

// Problem constants (fixed by the reference setup_inputs()).
#define J_     24
#define CIN_   32
#define COUT_  32
#define B_     8
#define T_     4096
#define R_     12
#define TT_    256                         // t per main-kernel block (8 waves x 32t)
#define POOLED_SZ_ (B_ * R_ * COUT_ * T_)  // 12,582,912
#define XT_ELEMS_  ((size_t)B_ * T_ * (J_ * CIN_))   // 25,165,824 bf16
#define NFRAG_     420                     // 70 edges * 3 kw * 2 co-tiles

typedef float  f32x4  __attribute__((ext_vector_type(4)));
typedef short  bf16x8 __attribute__((ext_vector_type(8)));
typedef unsigned short us8 __attribute__((ext_vector_type(8)));

// Compile-time adjacency (verified R1/R5): bit n of kAdjMask[i] <=> n in ADJ_LIST[i].
static constexpr unsigned kAdjMask[J_] = {
    0x0000000Fu, 0x00000013u, 0x00000025u, 0x00000049u, 0x00000092u, 0x00000124u,
    0x00000248u, 0x00000490u, 0x00000920u, 0x00007240u, 0x00000480u, 0x00000900u,
    0x00009200u, 0x00012200u, 0x00024200u, 0x00009000u, 0x00052000u, 0x000A4000u,
    0x00150000u, 0x002A0000u, 0x00540000u, 0x00A80000u, 0x00500000u, 0x00A00000u
};
static constexpr int kAdjOff[J_ + 1] = {
    0,4,7,10,13,16,19,22,25,28,33,35,37,40,43,46,48,51,54,57,60,63,66,68,70
};
// Flat edge index of (jout, nb), matching the ascending-per-joint flat order.
static constexpr int edge_of(int jout, int nb) {
    return kAdjOff[jout] + __builtin_popcount(kAdjMask[jout] & ((1u << nb) - 1u));
}
static constexpr int nedges(int j) { return kAdjOff[j + 1] - kAdjOff[j]; }
// LDS slot base (in 1KB frags) for edge (2*RGN+js -> nb): j0's edges first, then j1's.
static constexpr int local_base(int RGN, int js, int nb) {
    const int j = 2 * RGN + js;
    const int within = edge_of(j, nb) - kAdjOff[j];
    const int pre = js ? nedges(2 * RGN) : 0;
    return (pre + within) * 6;
}
// Union-neighborhood walk order for a region (ascending joint index).
static constexpr unsigned union_mask(int r) { return kAdjMask[2 * r] | kAdjMask[2 * r + 1]; }
static constexpr int union_count(int r) { return __builtin_popcount(union_mask(r)); }
static constexpr int union_nb(int r, int k) {
    unsigned m = union_mask(r);
    int idx = -1;
    for (int b = 0; b < J_; ++b) {
        if ((m >> b) & 1u) { if (++idx == k) return b; }
    }
    return -1;
}

// Device-side copies for the pack/aux kernel + runtime staging.
__device__ __constant__ unsigned int ADJMASK[J_] = {
    0x0000000Fu, 0x00000013u, 0x00000025u, 0x00000049u, 0x00000092u, 0x00000124u,
    0x00000248u, 0x00000490u, 0x00000920u, 0x00007240u, 0x00000480u, 0x00000900u,
    0x00009200u, 0x00012200u, 0x00024200u, 0x00009000u, 0x00052000u, 0x000A4000u,
    0x00150000u, 0x002A0000u, 0x00540000u, 0x00A80000u, 0x00500000u, 0x00A00000u
};
__device__ __constant__ int ADJ_FLAT[70] = {
    0,1,2,3,  0,1,4,  0,2,5,  0,3,6,  1,4,7,  2,5,8,  3,6,9,  4,7,10,  5,8,11,
    6,9,12,13,14,  7,10,  8,11,  9,12,15,  9,13,16,  9,14,17,  12,15,
    13,16,18,  14,17,19,  16,18,20,  17,19,21,  18,20,22,  19,21,23,  20,22,  21,23
};
__device__ __constant__ int ADJ_OFF[J_ + 1] = {
    0,4,7,10,13,16,19,22,25,28,33,35,37,40,43,46,48,51,54,57,60,63,66,68,70
};

static __device__ __forceinline__ unsigned short f2bf(float f) {
    unsigned u = __float_as_uint(f);
    unsigned r = (u + 0x7fffu + ((u >> 16) & 1u)) >> 16;   // RNE
    return (unsigned short)r;
}

// ---------------------------------------------------------------------------
// Pre-kernel 1: x fp32 [b][768][4096] -> xT bf16 [b][4096][768] via LDS tiles.
// (Already ~HBM-roofline: 148 MB at ~6 TB/s.)
// ---------------------------------------------------------------------------
__global__ __launch_bounds__(256)
void skel_transpose(const float* __restrict__ x, unsigned short* __restrict__ xT)
{
    __shared__ float xs[32][257];
    const int tid = threadIdx.x;
    const int tt0 = blockIdx.x * 256;   // t tile
    const int cg  = blockIdx.y;         // channel group of 32 (0..23)
    const int b   = blockIdx.z;

    const float* xp = x + ((size_t)b * (J_ * CIN_) + cg * 32) * T_ + tt0;
#pragma unroll
    for (int i = 0; i < 8; ++i) {
        const int idx = tid + i * 256;
        const int row = idx >> 6;            // 0..31
        const int c4  = (idx & 63) << 2;     // 0..252
        const float4 v = *(const float4*)(xp + (size_t)row * T_ + c4);
        xs[row][c4 + 0] = v.x; xs[row][c4 + 1] = v.y;
        xs[row][c4 + 2] = v.z; xs[row][c4 + 3] = v.w;
    }
    __syncthreads();

    union { unsigned short u[32]; uint4 q[4]; } pk;
#pragma unroll
    for (int c = 0; c < 32; ++c) pk.u[c] = f2bf(xs[c][tid]);
    unsigned short* dst = xT + ((size_t)b * T_ + tt0 + tid) * (J_ * CIN_) + cg * 32;
#pragma unroll
    for (int k = 0; k < 4; ++k) *(uint4*)(dst + k * 8) = pk.q[k];
}

// ---------------------------------------------------------------------------
// Pre-kernel 2: pack masked W blocks into per-lane MFMA A-fragments (bf16),
// k-slot map identical to the B side: ci = (lane>>4)*8 + elem. Block 420
// additionally writes the REGIONS / POST_ADJ constant outputs.
// ---------------------------------------------------------------------------
__global__ __launch_bounds__(64)
void skel_pack(const float* __restrict__ W, unsigned short* __restrict__ wsW,
               float* __restrict__ out_regions, float* __restrict__ out_post)
{
    const int fb = blockIdx.x;
    const int l  = threadIdx.x;          // 0..63
    if (fb == NFRAG_) {
        for (int i = l; i < J_; i += 64) out_regions[i] = (float)i;
        for (int i = l; i < R_ * R_; i += 64) {
            const int r1 = i / R_, r2 = i - r1 * R_;
            const unsigned m = ADJMASK[2 * r1] | ADJMASK[2 * r1 + 1];
            out_post[i] = ((m >> (2 * r2)) & 3u) ? 1.0f : 0.0f;
        }
        return;
    }
    const int cot = fb & 1;
    const int tmp = fb >> 1;
    const int kw  = tmp % 3;
    const int e   = tmp / 3;             // 0..69 flat edge index
    int jout = 0;
    while (ADJ_OFF[jout + 1] <= e) ++jout;
    const int nb = ADJ_FLAT[e];
    const int co = cot * 16 + (l & 15);
    const int hi = l >> 4;

    union { unsigned short u[8]; uint4 q; } pk;
#pragma unroll
    for (int j = 0; j < 8; ++j) {
        const int ci = hi * 8 + j;
        const float w = W[((size_t)(jout * COUT_ + co) * (J_ * CIN_) + (nb * CIN_ + ci)) * 3 + kw];
        pk.u[j] = f2bf(w);
    }
    *(uint4*)(wsW + (size_t)fb * 512 + l * 8) = pk.q;
}

// ---------------------------------------------------------------------------
// Main kernel. 8 waves x 32t. A-fragments in LDS (immediate offsets).
// NEW: explicit 2-deep software pipeline over the union-neighbor walk —
// step K+1's 6 B-loads are issued BEFORE step K's MFMAs, so the vmcnt wait
// for step K overlaps step K+1's memory latency (T14 issue-early).
// ---------------------------------------------------------------------------
template<int RGN, int NB>
__device__ __forceinline__ void load_b(const unsigned short* __restrict__ xTb,
                                       int tw, bf16x8 bfr[3][2])
{
#pragma unroll
    for (int kw = 0; kw < 3; ++kw) {
#pragma unroll
        for (int sl = 0; sl < 2; ++sl) {
            const int t  = tw + sl * 16 + kw - 1;
            const int tc = t < 0 ? 0 : (t > T_ - 1 ? T_ - 1 : t);
            us8 v = *(const us8*)(xTb + (size_t)tc * (J_ * CIN_) + NB * CIN_);
            if ((unsigned)t >= (unsigned)T_) {
                const us8 z = {0, 0, 0, 0, 0, 0, 0, 0};
                v = z;
            }
            bfr[kw][sl] = (bf16x8)v;
        }
    }
}

template<int RGN, int NB>
__device__ __forceinline__ void compute_b(const unsigned short* __restrict__ ldsl,
                                          const bf16x8 bfr[3][2], f32x4 acc[2][2][2])
{
    constexpr bool e0 = (kAdjMask[2 * RGN] >> NB) & 1u;
    constexpr bool e1 = (kAdjMask[2 * RGN + 1] >> NB) & 1u;
    if constexpr (e0) {
        constexpr int LB = local_base(RGN, 0, NB);
#pragma unroll
        for (int kw = 0; kw < 3; ++kw)
#pragma unroll
            for (int cot = 0; cot < 2; ++cot) {
                const bf16x8 a = *(const bf16x8*)(ldsl + (size_t)(LB + kw * 2 + cot) * 512);
#pragma unroll
                for (int sl = 0; sl < 2; ++sl)
                    acc[0][cot][sl] = __builtin_amdgcn_mfma_f32_16x16x32_bf16(
                        a, bfr[kw][sl], acc[0][cot][sl], 0, 0, 0);
            }
    }
    if constexpr (e1) {
        constexpr int LB = local_base(RGN, 1, NB);
#pragma unroll
        for (int kw = 0; kw < 3; ++kw)
#pragma unroll
            for (int cot = 0; cot < 2; ++cot) {
                const bf16x8 a = *(const bf16x8*)(ldsl + (size_t)(LB + kw * 2 + cot) * 512);
#pragma unroll
                for (int sl = 0; sl < 2; ++sl)
                    acc[1][cot][sl] = __builtin_amdgcn_mfma_f32_16x16x32_bf16(
                        a, bfr[kw][sl], acc[1][cot][sl], 0, 0, 0);
            }
    }
}

template<int RGN, int K>
__device__ __forceinline__ void pipe_step(const unsigned short* __restrict__ xTb,
                                          const unsigned short* __restrict__ ldsl,
                                          int tw, bf16x8 b0[3][2], bf16x8 b1[3][2],
                                          f32x4 acc[2][2][2])
{
    constexpr int N = union_count(RGN);
    // Issue next step's loads first (into the alternate buffer)...
    if constexpr (K + 1 < N) {
        if constexpr ((K + 1) & 1) load_b<RGN, union_nb(RGN, K + 1)>(xTb, tw, b1);
        else                       load_b<RGN, union_nb(RGN, K + 1)>(xTb, tw, b0);
    }
    // ...then compute this step (waits only on its own, already-old loads).
    if constexpr (K & 1) compute_b<RGN, union_nb(RGN, K)>(ldsl, b1, acc);
    else                 compute_b<RGN, union_nb(RGN, K)>(ldsl, b0, acc);
}

template<int RGN, int... Ks>
__device__ __forceinline__ void region_pipe(std::integer_sequence<int, Ks...>,
                                            const unsigned short* __restrict__ xTb,
                                            const unsigned short* __restrict__ ldsl,
                                            int tw, f32x4 acc[2][2][2])
{
    bf16x8 b0[3][2], b1[3][2];
    load_b<RGN, union_nb(RGN, 0)>(xTb, tw, b0);      // prologue fill
    (pipe_step<RGN, Ks>(xTb, ldsl, tw, b0, b1, acc), ...);
}

template<int RGN>
__device__ __forceinline__ void run_region(const unsigned short* __restrict__ xTb,
                                           const unsigned short* __restrict__ ldsl,
                                           int tw, f32x4 acc[2][2][2])
{
    region_pipe<RGN>(std::make_integer_sequence<int, union_count(RGN)>{},
                     xTb, ldsl, tw, acc);
}

__global__ __launch_bounds__(512, 4)
void skel_main(const unsigned short* __restrict__ xT,
               const unsigned short* __restrict__ wsW,
               const float* __restrict__ bias, float* __restrict__ out)
{
    // XCD-chunked swizzle (grid 1536 = 8*192, bijective): the 12 regions of a
    // (b,t-tile) group land on one XCD so shared xT rows stay L2-resident.
    const int i    = blockIdx.x;          // 0..1535
    const int xcd  = i & 7;
    const int slot = i >> 3;              // 0..191
    const int r    = slot % R_;
    const int gi   = slot / R_;           // 0..15
    const int g    = xcd + 8 * gi;        // (b,t-tile) group 0..127
    const int b    = g >> 4;
    const int t0   = (g & 15) * TT_;

    const int tid  = threadIdx.x;
    const int wv   = tid >> 6;            // 0..7
    const int lane = tid & 63;
    const int l15  = lane & 15;
    const int hi   = lane >> 4;

    // --- Stage this region's A-fragments into LDS (coalesced uint4 copy). ---
    __shared__ uint4 ldsAq[3072];          // 48 KB: max 8 edges * 6 frags * 1KB
    const int j0 = 2 * r, j1 = 2 * r + 1;
    const int n0 = ADJ_OFF[j0 + 1] - ADJ_OFF[j0];
    const int n1 = ADJ_OFF[j1 + 1] - ADJ_OFF[j1];
    {
        const uint4* s0 = (const uint4*)(wsW + (size_t)ADJ_OFF[j0] * 6 * 512);
        const uint4* s1 = (const uint4*)(wsW + (size_t)ADJ_OFF[j1] * 6 * 512);
        const int q0 = n0 * 384;           // 1KB frag = 64 uint4
        const int q1 = n1 * 384;
        for (int c = tid; c < q0; c += 512) ldsAq[c] = s0[c];
        for (int c = tid; c < q1; c += 512) ldsAq[q0 + c] = s1[c];
    }
    __syncthreads();

    f32x4 acc[2][2][2];                   // [joint][co_tile][subtile]
#pragma unroll
    for (int a = 0; a < 2; ++a)
#pragma unroll
        for (int c = 0; c < 2; ++c)
#pragma unroll
            for (int s = 0; s < 2; ++s) acc[a][c][s] = (f32x4){0.f, 0.f, 0.f, 0.f};

    const unsigned short* xTb  = xT + (size_t)b * T_ * (J_ * CIN_) + hi * 8;
    const unsigned short* ldsl = (const unsigned short*)ldsAq + lane * 8;
    const int tw = t0 + wv * 32 + l15;    // lane's t for sl=0, kw=1

    switch (r) {
        case 0:  run_region<0>(xTb, ldsl, tw, acc); break;
        case 1:  run_region<1>(xTb, ldsl, tw, acc); break;
        case 2:  run_region<2>(xTb, ldsl, tw, acc); break;
        case 3:  run_region<3>(xTb, ldsl, tw, acc); break;
        case 4:  run_region<4>(xTb, ldsl, tw, acc); break;
        case 5:  run_region<5>(xTb, ldsl, tw, acc); break;
        case 6:  run_region<6>(xTb, ldsl, tw, acc); break;
        case 7:  run_region<7>(xTb, ldsl, tw, acc); break;
        case 8:  run_region<8>(xTb, ldsl, tw, acc); break;
        case 9:  run_region<9>(xTb, ldsl, tw, acc); break;
        case 10: run_region<10>(xTb, ldsl, tw, acc); break;
        default: run_region<11>(xTb, ldsl, tw, acc); break;
    }

    // Epilogue: bias + leakyReLU + pair mean. D layout: col=lane&15 (t),
    // row=(lane>>4)*4+q (co within 16-tile). [verified m89]
#pragma unroll
    for (int cot = 0; cot < 2; ++cot) {
#pragma unroll
        for (int q = 0; q < 4; ++q) {
            const int co  = cot * 16 + hi * 4 + q;
            const float bb0 = bias[j0 * COUT_ + co];
            const float bb1 = bias[j1 * COUT_ + co];
            float* orow = out + ((size_t)b * (R_ * COUT_) + r * COUT_ + co) * T_
                          + t0 + wv * 32 + l15;
#pragma unroll
            for (int sl = 0; sl < 2; ++sl) {
                float y0 = acc[0][cot][sl][q] + bb0;
                y0 = (y0 > 0.f) ? y0 : 0.2f * y0;
                float y1 = acc[1][cot][sl][q] + bb1;
                y1 = (y1 > 0.f) ? y1 : 0.2f * y1;
                orow[sl * 16] = 0.5f * (y0 + y1);
            }
        }
    }
}

extern "C" void kernel_launch(void* const* d_in, const int* in_sizes, int n_in,
                              void* d_out, int out_size, void* d_ws, size_t ws_size,
                              hipStream_t stream)
{
    const float* x    = (const float*)d_in[0];
    const float* W    = (const float*)d_in[1];
    const float* bias = (const float*)d_in[2];
    float* out = (float*)d_out;

    unsigned short* xT  = (unsigned short*)d_ws;                 // 48 MiB bf16
    unsigned short* wsW = xT + XT_ELEMS_;                        // +420 KiB frags

    dim3 tgrid(T_ / 256, J_ * CIN_ / 32, B_);
    skel_transpose<<<tgrid, 256, 0, stream>>>(x, xT);

    float* out_regions = out + POOLED_SZ_;
    float* out_post    = out_regions + J_;
    skel_pack<<<NFRAG_ + 1, 64, 0, stream>>>(W, wsW, out_regions, out_post);

    skel_main<<<(T_ / TT_) * R_ * B_, 512, 0, stream>>>(xT, wsW, bias, out);
}

// Round 12
// 84.537 us; speedup vs baseline: 1.3812x; 1.2074x over previous
//
#include <hip/hip_runtime.h>
#include <hip/hip_bf16.h>
#include <utility>

// Problem constants (fixed by the reference setup_inputs()).
#define J_     24
#define CIN_   32
#define COUT_  32
#define B_     8
#define T_     4096
#define R_     12
#define TT_    128                         // t per main-kernel block (8 waves x 16t)
#define POOLED_SZ_ (B_ * R_ * COUT_ * T_)  // 12,582,912
#define XT_ELEMS_  ((size_t)B_ * T_ * (J_ * CIN_))   // 25,165,824 bf16
#define NFRAG_     420                     // 70 edges * 3 kw * 2 co-tiles
#define BSLAB_     9216                    // 144 rows x 64 B per neighbor slab
#define ALDS_      49152                   // A-fragment LDS region (48 KB)

typedef float  f32x4  __attribute__((ext_vector_type(4)));
typedef short  bf16x8 __attribute__((ext_vector_type(8)));
typedef unsigned short us8 __attribute__((ext_vector_type(8)));

// Compile-time adjacency (verified R1/R5): bit n of kAdjMask[i] <=> n in ADJ_LIST[i].
static constexpr unsigned kAdjMask[J_] = {
    0x0000000Fu, 0x00000013u, 0x00000025u, 0x00000049u, 0x00000092u, 0x00000124u,
    0x00000248u, 0x00000490u, 0x00000920u, 0x00007240u, 0x00000480u, 0x00000900u,
    0x00009200u, 0x00012200u, 0x00024200u, 0x00009000u, 0x00052000u, 0x000A4000u,
    0x00150000u, 0x002A0000u, 0x00540000u, 0x00A80000u, 0x00500000u, 0x00A00000u
};
static constexpr int kAdjOff[J_ + 1] = {
    0,4,7,10,13,16,19,22,25,28,33,35,37,40,43,46,48,51,54,57,60,63,66,68,70
};
static constexpr int edge_of(int jout, int nb) {
    return kAdjOff[jout] + __builtin_popcount(kAdjMask[jout] & ((1u << nb) - 1u));
}
static constexpr int nedges(int j) { return kAdjOff[j + 1] - kAdjOff[j]; }
// LDS slot base (in 1KB frags) for edge (2*RGN+js -> nb): j0's edges first, then j1's.
static constexpr int local_base(int RGN, int js, int nb) {
    const int j = 2 * RGN + js;
    const int within = edge_of(j, nb) - kAdjOff[j];
    const int pre = js ? nedges(2 * RGN) : 0;
    return (pre + within) * 6;
}
// Union-neighborhood helpers.
static constexpr unsigned union_mask(int r) { return kAdjMask[2 * r] | kAdjMask[2 * r + 1]; }
static constexpr int union_rank(int r, int nb) {
    return __builtin_popcount(union_mask(r) & ((1u << nb) - 1u));
}

// Device-side tables for runtime staging / pack kernels.
__device__ __constant__ unsigned int ADJMASK[J_] = {
    0x0000000Fu, 0x00000013u, 0x00000025u, 0x00000049u, 0x00000092u, 0x00000124u,
    0x00000248u, 0x00000490u, 0x00000920u, 0x00007240u, 0x00000480u, 0x00000900u,
    0x00009200u, 0x00012200u, 0x00024200u, 0x00009000u, 0x00052000u, 0x000A4000u,
    0x00150000u, 0x002A0000u, 0x00540000u, 0x00A80000u, 0x00500000u, 0x00A00000u
};
__device__ __constant__ int ADJ_FLAT[70] = {
    0,1,2,3,  0,1,4,  0,2,5,  0,3,6,  1,4,7,  2,5,8,  3,6,9,  4,7,10,  5,8,11,
    6,9,12,13,14,  7,10,  8,11,  9,12,15,  9,13,16,  9,14,17,  12,15,
    13,16,18,  14,17,19,  16,18,20,  17,19,21,  18,20,22,  19,21,23,  20,22,  21,23
};
__device__ __constant__ int ADJ_OFF[J_ + 1] = {
    0,4,7,10,13,16,19,22,25,28,33,35,37,40,43,46,48,51,54,57,60,63,66,68,70
};
// Union walk tables (ascending; verified against kAdjMask ORs).
__device__ __constant__ int UNION_CNT[R_] = {5,5,6,6,8,4,5,5,6,6,6,4};
__device__ __constant__ int UNION_NB[R_][8] = {
    {0,1,2,3,4,0,0,0},      {0,2,3,5,6,0,0,0},      {1,2,4,5,7,8,0,0},
    {3,4,6,7,9,10,0,0},     {5,6,8,9,11,12,13,14},  {7,8,10,11,0,0,0,0},
    {9,12,13,15,16,0,0,0},  {9,12,14,15,17,0,0,0},  {13,14,16,17,18,19,0,0},
    {16,17,18,19,20,21,0,0},{18,19,20,21,22,23,0,0},{20,21,22,23,0,0,0,0}
};

static __device__ __forceinline__ unsigned short f2bf(float f) {
    unsigned u = __float_as_uint(f);
    unsigned r = (u + 0x7fffu + ((u >> 16) & 1u)) >> 16;   // RNE
    return (unsigned short)r;
}

// Async global->LDS, 16 B per lane. LDS dest is wave-uniform; source is per-lane.
static __device__ __forceinline__ void gload_lds16(const void* g, void* l) {
    __builtin_amdgcn_global_load_lds(
        (const __attribute__((address_space(1))) unsigned int*)g,
        (__attribute__((address_space(3))) unsigned int*)l, 16, 0, 0);
}

// ---------------------------------------------------------------------------
// Pre-kernel 1: x fp32 [b][768][4096] -> xT bf16 [b][4096][768] via LDS tiles.
// (Already ~HBM-roofline: 148 MB at ~6 TB/s.)
// ---------------------------------------------------------------------------
__global__ __launch_bounds__(256)
void skel_transpose(const float* __restrict__ x, unsigned short* __restrict__ xT)
{
    __shared__ float xs[32][257];
    const int tid = threadIdx.x;
    const int tt0 = blockIdx.x * 256;   // t tile
    const int cg  = blockIdx.y;         // channel group of 32 (0..23)
    const int b   = blockIdx.z;

    const float* xp = x + ((size_t)b * (J_ * CIN_) + cg * 32) * T_ + tt0;
#pragma unroll
    for (int i = 0; i < 8; ++i) {
        const int idx = tid + i * 256;
        const int row = idx >> 6;            // 0..31
        const int c4  = (idx & 63) << 2;     // 0..252
        const float4 v = *(const float4*)(xp + (size_t)row * T_ + c4);
        xs[row][c4 + 0] = v.x; xs[row][c4 + 1] = v.y;
        xs[row][c4 + 2] = v.z; xs[row][c4 + 3] = v.w;
    }
    __syncthreads();

    union { unsigned short u[32]; uint4 q[4]; } pk;
#pragma unroll
    for (int c = 0; c < 32; ++c) pk.u[c] = f2bf(xs[c][tid]);
    unsigned short* dst = xT + ((size_t)b * T_ + tt0 + tid) * (J_ * CIN_) + cg * 32;
#pragma unroll
    for (int k = 0; k < 4; ++k) *(uint4*)(dst + k * 8) = pk.q[k];
}

// ---------------------------------------------------------------------------
// Pre-kernel 2: pack masked W blocks into per-lane MFMA A-fragments (bf16),
// k-slot map identical to the B side: ci = (lane>>4)*8 + elem. Block 420
// additionally writes the REGIONS / POST_ADJ constant outputs.
// ---------------------------------------------------------------------------
__global__ __launch_bounds__(64)
void skel_pack(const float* __restrict__ W, unsigned short* __restrict__ wsW,
               float* __restrict__ out_regions, float* __restrict__ out_post)
{
    const int fb = blockIdx.x;
    const int l  = threadIdx.x;          // 0..63
    if (fb == NFRAG_) {
        for (int i = l; i < J_; i += 64) out_regions[i] = (float)i;
        for (int i = l; i < R_ * R_; i += 64) {
            const int r1 = i / R_, r2 = i - r1 * R_;
            const unsigned m = ADJMASK[2 * r1] | ADJMASK[2 * r1 + 1];
            out_post[i] = ((m >> (2 * r2)) & 3u) ? 1.0f : 0.0f;
        }
        return;
    }
    const int cot = fb & 1;
    const int tmp = fb >> 1;
    const int kw  = tmp % 3;
    const int e   = tmp / 3;             // 0..69 flat edge index
    int jout = 0;
    while (ADJ_OFF[jout + 1] <= e) ++jout;
    const int nb = ADJ_FLAT[e];
    const int co = cot * 16 + (l & 15);
    const int hi = l >> 4;

    union { unsigned short u[8]; uint4 q; } pk;
#pragma unroll
    for (int j = 0; j < 8; ++j) {
        const int ci = hi * 8 + j;
        const float w = W[((size_t)(jout * COUT_ + co) * (J_ * CIN_) + (nb * CIN_ + ci)) * 3 + kw];
        pk.u[j] = f2bf(w);
    }
    *(uint4*)(wsW + (size_t)fb * 512 + l * 8) = pk.q;
}

// ---------------------------------------------------------------------------
// Main kernel. Per block: stage A-frags (48 KB) + union-neighbor B-slab
// (global_load_lds, XOR-swizzled source) into LDS, one barrier, then the
// entire conv runs from LDS: ds_read_b128 A + B -> MFMA. No global loads
// in the inner loop.
// ---------------------------------------------------------------------------
template<int RGN, int NB>
__device__ __forceinline__ void nb_step(const unsigned char* __restrict__ ldsB,
                                        const unsigned short* __restrict__ ldsl,
                                        int rtb, int hi, f32x4 acc[2][2])
{
    constexpr bool e0 = (kAdjMask[2 * RGN] >> NB) & 1u;
    constexpr bool e1 = (kAdjMask[2 * RGN + 1] >> NB) & 1u;
    if constexpr (!(e0 || e1)) return;

    constexpr int SLAB = union_rank(RGN, NB);
    const unsigned char* bbase = ldsB + SLAB * BSLAB_;

    bf16x8 bfr[3];
#pragma unroll
    for (int kw = 0; kw < 3; ++kw) {
        const int rt = rtb + kw;                      // 0..129
        bfr[kw] = *(const bf16x8*)(bbase + rt * 64 + ((hi ^ (rt & 3)) << 4));
    }
    if constexpr (e0) {
        constexpr int LB = local_base(RGN, 0, NB);
#pragma unroll
        for (int kw = 0; kw < 3; ++kw)
#pragma unroll
            for (int cot = 0; cot < 2; ++cot) {
                const bf16x8 a = *(const bf16x8*)(ldsl + (size_t)(LB + kw * 2 + cot) * 512);
                acc[0][cot] = __builtin_amdgcn_mfma_f32_16x16x32_bf16(
                    a, bfr[kw], acc[0][cot], 0, 0, 0);
            }
    }
    if constexpr (e1) {
        constexpr int LB = local_base(RGN, 1, NB);
#pragma unroll
        for (int kw = 0; kw < 3; ++kw)
#pragma unroll
            for (int cot = 0; cot < 2; ++cot) {
                const bf16x8 a = *(const bf16x8*)(ldsl + (size_t)(LB + kw * 2 + cot) * 512);
                acc[1][cot] = __builtin_amdgcn_mfma_f32_16x16x32_bf16(
                    a, bfr[kw], acc[1][cot], 0, 0, 0);
            }
    }
}

template<int RGN, int... NBs>
__device__ __forceinline__ void region_all(std::integer_sequence<int, NBs...>,
                                           const unsigned char* __restrict__ ldsB,
                                           const unsigned short* __restrict__ ldsl,
                                           int rtb, int hi, f32x4 acc[2][2])
{
    (nb_step<RGN, NBs>(ldsB, ldsl, rtb, hi, acc), ...);
}

__global__ __launch_bounds__(512, 2)
void skel_main(const unsigned short* __restrict__ xT,
               const unsigned short* __restrict__ wsW,
               const float* __restrict__ bias, float* __restrict__ out)
{
    // XCD-chunked swizzle (grid 3072 = 8*384, bijective): the 12 regions of a
    // (b,t-tile) group land on one XCD so shared xT rows stay L2-resident.
    const int i    = blockIdx.x;          // 0..3071
    const int xcd  = i & 7;
    const int slot = i >> 3;              // 0..383
    const int r    = slot % R_;
    const int gi   = slot / R_;           // 0..31
    const int g    = xcd + 8 * gi;        // (b,t-tile) group 0..255
    const int b    = g >> 5;
    const int t0   = (g & 31) * TT_;

    const int tid  = threadIdx.x;
    const int wv   = tid >> 6;            // 0..7
    const int lane = tid & 63;
    const int l15  = lane & 15;
    const int hi   = lane >> 4;

    __shared__ __align__(16) unsigned char lds[ALDS_ + 8 * BSLAB_];  // 122,880 B
    unsigned short* ldsA = (unsigned short*)lds;
    unsigned char*  ldsB = lds + ALDS_;

    const int j0 = 2 * r, j1 = 2 * r + 1;

    // --- B-stage: wave w stages union-neighbor w via 9x global_load_lds. ---
    // LDS layout per slab: row rt (144 rows x 64 B), chunk slot s holds ci-chunk
    // (s ^ (rt&3)) -- inverse-XOR applied on the per-lane GLOBAL source so the
    // read-side XOR sees linear data (both-sides involution).
    {
        const int NU = UNION_CNT[r];
        if (wv < NU) {
            const int nb = UNION_NB[r][wv];
            const unsigned short* gb = xT + (size_t)b * T_ * (J_ * CIN_) + nb * CIN_;
            unsigned char* ldst = ldsB + wv * BSLAB_;
            const int lrow = lane >> 2, lslot = lane & 3;
#pragma unroll
            for (int L = 0; L < 9; ++L) {
                const int rt = L * 16 + lrow;
                int t = t0 - 1 + rt;
                t = t < 0 ? 0 : (t > T_ - 1 ? T_ - 1 : t);
                const unsigned short* gsrc = gb + (size_t)t * (J_ * CIN_)
                                             + ((lslot ^ (rt & 3)) << 3);
                gload_lds16(gsrc, ldst + L * 1024);
            }
        }
    }
    // --- A-stage: coalesced uint4 copy of this region's fragments. ---
    {
        const int n0 = ADJ_OFF[j0 + 1] - ADJ_OFF[j0];
        const int n1 = ADJ_OFF[j1 + 1] - ADJ_OFF[j1];
        const uint4* s0 = (const uint4*)(wsW + (size_t)ADJ_OFF[j0] * 6 * 512);
        const uint4* s1 = (const uint4*)(wsW + (size_t)ADJ_OFF[j1] * 6 * 512);
        uint4* dA = (uint4*)ldsA;
        const int q0 = n0 * 384;           // 1KB frag = 64 uint4
        const int q1 = n1 * 384;
        for (int c = tid; c < q0; c += 512) dA[c] = s0[c];
        for (int c = tid; c < q1; c += 512) dA[q0 + c] = s1[c];
    }
    __syncthreads();                       // drains vmcnt (gload_lds) + lgkm

    // --- SAME-padding: zero the pad row (t=-1 or t=T) in every slab. ---
    if (t0 == 0 || t0 == T_ - TT_) {
        const int zr = (t0 == 0) ? 0 : (TT_ + 1);
        if (tid < 32) {
            const uint4 z = {0u, 0u, 0u, 0u};
            *(uint4*)(ldsB + (tid >> 2) * BSLAB_ + zr * 64 + (tid & 3) * 16) = z;
        }
        __syncthreads();
    }

    f32x4 acc[2][2];                       // [joint][co_tile]
#pragma unroll
    for (int a = 0; a < 2; ++a)
#pragma unroll
        for (int c = 0; c < 2; ++c) acc[a][c] = (f32x4){0.f, 0.f, 0.f, 0.f};

    const unsigned short* ldsl = ldsA + lane * 8;
    const int rtb = wv * 16 + l15;         // local row for kw=0 (t-1 shift)

    using Seq = std::make_integer_sequence<int, J_>;
    switch (r) {
        case 0:  region_all<0>(Seq{}, ldsB, ldsl, rtb, hi, acc); break;
        case 1:  region_all<1>(Seq{}, ldsB, ldsl, rtb, hi, acc); break;
        case 2:  region_all<2>(Seq{}, ldsB, ldsl, rtb, hi, acc); break;
        case 3:  region_all<3>(Seq{}, ldsB, ldsl, rtb, hi, acc); break;
        case 4:  region_all<4>(Seq{}, ldsB, ldsl, rtb, hi, acc); break;
        case 5:  region_all<5>(Seq{}, ldsB, ldsl, rtb, hi, acc); break;
        case 6:  region_all<6>(Seq{}, ldsB, ldsl, rtb, hi, acc); break;
        case 7:  region_all<7>(Seq{}, ldsB, ldsl, rtb, hi, acc); break;
        case 8:  region_all<8>(Seq{}, ldsB, ldsl, rtb, hi, acc); break;
        case 9:  region_all<9>(Seq{}, ldsB, ldsl, rtb, hi, acc); break;
        case 10: region_all<10>(Seq{}, ldsB, ldsl, rtb, hi, acc); break;
        default: region_all<11>(Seq{}, ldsB, ldsl, rtb, hi, acc); break;
    }

    // Epilogue: bias + leakyReLU + pair mean. D layout: col=lane&15 (t),
    // row=(lane>>4)*4+q (co within 16-tile). [verified m89]
#pragma unroll
    for (int cot = 0; cot < 2; ++cot) {
#pragma unroll
        for (int q = 0; q < 4; ++q) {
            const int co  = cot * 16 + hi * 4 + q;
            float y0 = acc[0][cot][q] + bias[j0 * COUT_ + co];
            y0 = (y0 > 0.f) ? y0 : 0.2f * y0;
            float y1 = acc[1][cot][q] + bias[j1 * COUT_ + co];
            y1 = (y1 > 0.f) ? y1 : 0.2f * y1;
            out[((size_t)b * (R_ * COUT_) + r * COUT_ + co) * T_
                + t0 + wv * 16 + l15] = 0.5f * (y0 + y1);
        }
    }
}

extern "C" void kernel_launch(void* const* d_in, const int* in_sizes, int n_in,
                              void* d_out, int out_size, void* d_ws, size_t ws_size,
                              hipStream_t stream)
{
    const float* x    = (const float*)d_in[0];
    const float* W    = (const float*)d_in[1];
    const float* bias = (const float*)d_in[2];
    float* out = (float*)d_out;

    unsigned short* xT  = (unsigned short*)d_ws;                 // 48 MiB bf16
    unsigned short* wsW = xT + XT_ELEMS_;                        // +420 KiB frags

    dim3 tgrid(T_ / 256, J_ * CIN_ / 32, B_);
    skel_transpose<<<tgrid, 256, 0, stream>>>(x, xT);

    float* out_regions = out + POOLED_SZ_;
    float* out_post    = out_regions + J_;
    skel_pack<<<NFRAG_ + 1, 64, 0, stream>>>(W, wsW, out_regions, out_post);

    skel_main<<<(T_ / TT_) * R_ * B_, 512, 0, stream>>>(xT, wsW, bias, out);
}